// Round 7
// baseline (99.778 us; speedup 1.0000x reference)
//
#include <hip/hip_runtime.h>
#include <hip/hip_bf16.h>
#include <stdint.h>

// SelfBallPointQuery: B=16, C=3, N=2048, RADIUS^2=0.04, MAX_SAMPLES=64.
// For each (b,i): first 64 ascending j with |x_i - x_j|^2 < 0.04, padded with
// the first hit. int64 reference output -> int32 device buffer.
//
// R7 = R6 with SRD word3 = 0x00020000 (raw untyped dword access). R6 passed
// flags=0 -> invalid descriptor -> ALL stores silently dropped (output stayed
// memset-0, absmax 2048 = the all-zero signature).
//
// Branch-free inner loop: per-query SRDs with num_records=256 B so the
// hardware bounds check drops stores with pos>=64 and (via a cndmask'd huge
// voffset) non-pred lanes -- zero branches / exec manipulation per q-iter.

#define B_DIM 16
#define N_PTS 2048
#define K_OUT 64
#define R2 0.04f
#define QPW 8                           // queries per wave
#define WAVES_PER_BLOCK 4
#define QPB (QPW * WAVES_PER_BLOCK)     // 32 queries per block
#define NCHUNK (N_PTS / 64)             // 32

__global__ __launch_bounds__(256) void ball_query_kernel(
    const float* __restrict__ pcs,   // (B, 3, N)
    int* __restrict__ out)           // (B, N, 64) int32
{
    __shared__ float xs4[N_PTS * 4];  // float4-padded xyz_, 32 KB

    const int b     = blockIdx.x / (N_PTS / QPB);
    const int qblk  = blockIdx.x % (N_PTS / QPB);
    const int tid   = threadIdx.x;
    const int wave  = tid >> 6;
    const int lane  = tid & 63;

    // Stage cloud b: 3 coalesced global reads per point, one b128 LDS write
    const float* src = pcs + (size_t)b * 3 * N_PTS;
    for (int j = tid; j < N_PTS; j += 256) {
        float4 p;
        p.x = src[0 * N_PTS + j];
        p.y = src[1 * N_PTS + j];
        p.z = src[2 * N_PTS + j];
        p.w = 0.0f;
        *(float4*)&xs4[j * 4] = p;
    }
    __syncthreads();

    const int i0 = qblk * QPB + wave * QPW;    // first query of this wave

    float qx[QPW], qy[QPW], qz[QPW];
    int   count[QPW], first[QPW];
    bool  havef[QPW];
    __amdgpu_buffer_rsrc_t srd[QPW];
    int* const outw = out + ((size_t)b * N_PTS + i0) * K_OUT;

    #pragma unroll
    for (int q = 0; q < QPW; ++q) {
        qx[q] = xs4[(i0 + q) * 4 + 0];
        qy[q] = xs4[(i0 + q) * 4 + 1];
        qz[q] = xs4[(i0 + q) * 4 + 2];
        count[q] = 0; first[q] = 0; havef[q] = false;
        // stride=0, num_records=256 bytes (64 int slots),
        // word3=0x00020000 = raw untyped dword access (gfx9 data format)
        srd[q] = __builtin_amdgcn_make_buffer_rsrc(
            (void*)(outw + q * K_OUT), (short)0, K_OUT * 4, 0x00020000);
    }

    for (int chunk = 0; chunk < NCHUNK; ++chunk) {
        const int j = chunk * 64 + lane;
        const float4 p = *(const float4*)&xs4[j * 4];

        #pragma unroll
        for (int q = 0; q < QPW; ++q) {
            const float dx = p.x - qx[q];
            const float dy = p.y - qy[q];
            const float dz = p.z - qz[q];
            // exact numpy f32 association, no FMA contraction:
            const float d2 = __fadd_rn(__fadd_rn(__fmul_rn(dx, dx),
                                                 __fmul_rn(dy, dy)),
                                       __fmul_rn(dz, dz));
            const bool pred = d2 < R2;
            const unsigned long long mask = __ballot(pred);

            // branchless first-hit bookkeeping (wave-uniform scalar selects)
            const int cz = (mask != 0ull) ? (int)__builtin_ctzll(mask) : 0;
            first[q] = havef[q] ? first[q] : (chunk * 64 + cz);
            havef[q] = havef[q] | (mask != 0ull);

            // ascending write slot: count + prefix-popcount below this lane
            const int before = __builtin_amdgcn_mbcnt_hi(
                (unsigned int)(mask >> 32),
                __builtin_amdgcn_mbcnt_lo((unsigned int)mask, 0u));
            const unsigned pos4 = (unsigned)((count[q] + before) << 2);
            // non-pred lanes -> huge voffset (dropped); pos>=64 -> >=256 (dropped)
            const unsigned voff = pred ? pos4 : 0x40000000u;
            __builtin_amdgcn_raw_buffer_store_b32(j, srd[q], voff, 0, 0);

            count[q] += (int)__popcll(mask);           // wave-uniform
        }
    }

    // pad tails with the first hit; lanes with count+lane >= 64 are OOB-dropped
    #pragma unroll
    for (int q = 0; q < QPW; ++q) {
        const unsigned voffp = (unsigned)((count[q] + lane) << 2);
        __builtin_amdgcn_raw_buffer_store_b32(first[q], srd[q], voffp, 0, 0);
    }
}

extern "C" void kernel_launch(void* const* d_in, const int* in_sizes, int n_in,
                              void* d_out, int out_size, void* d_ws, size_t ws_size,
                              hipStream_t stream) {
    const float* pcs = (const float*)d_in[0];
    int* out = (int*)d_out;
    const int grid = B_DIM * (N_PTS / QPB);   // 1024 blocks
    ball_query_kernel<<<grid, 256, 0, stream>>>(pcs, out);
}

// Round 8
// 94.131 us; speedup vs baseline: 1.0600x; 1.0600x over previous
//
#include <hip/hip_runtime.h>
#include <hip/hip_bf16.h>
#include <stdint.h>

// SelfBallPointQuery: B=16, C=3, N=2048, RADIUS^2=0.04, MAX_SAMPLES=64.
// For each (b,i): first 64 ascending j with |x_i - x_j|^2 < 0.04, padded with
// the first hit. int64 reference output -> int32 device buffer.
//
// R8 = R7 body (branch-free, per-query SRD with HW OOB-drop stores) at 2x
// occupancy: 512-thread blocks (8 waves), QPW=4, grid 1024 -> 4 blocks/CU x
// 8 waves = 32 waves/CU (was 16). R7 post-mortem: q-iter latency chain
// (v_cmp -> ballot SGPR -> SALU -> mbcnt -> store) needs wave-level
// overlap, not more ILP; VGPR=44 fits the 64-reg budget of 8 waves/SIMD.

#define B_DIM 16
#define N_PTS 2048
#define K_OUT 64
#define R2 0.04f
#define QPW 4                           // queries per wave
#define WAVES_PER_BLOCK 8
#define QPB (QPW * WAVES_PER_BLOCK)     // 32 queries per block
#define NCHUNK (N_PTS / 64)             // 32
#define BLOCK_T (WAVES_PER_BLOCK * 64)  // 512

__global__ __launch_bounds__(BLOCK_T, 8) void ball_query_kernel(
    const float* __restrict__ pcs,   // (B, 3, N)
    int* __restrict__ out)           // (B, N, 64) int32
{
    __shared__ float xs4[N_PTS * 4];  // float4-padded xyz_, 32 KB

    const int b     = blockIdx.x / (N_PTS / QPB);
    const int qblk  = blockIdx.x % (N_PTS / QPB);
    const int tid   = threadIdx.x;
    const int wave  = tid >> 6;
    const int lane  = tid & 63;

    // Stage cloud b: 3 coalesced global reads per point, one b128 LDS write
    const float* src = pcs + (size_t)b * 3 * N_PTS;
    for (int j = tid; j < N_PTS; j += BLOCK_T) {
        float4 p;
        p.x = src[0 * N_PTS + j];
        p.y = src[1 * N_PTS + j];
        p.z = src[2 * N_PTS + j];
        p.w = 0.0f;
        *(float4*)&xs4[j * 4] = p;
    }
    __syncthreads();

    const int i0 = qblk * QPB + wave * QPW;    // first query of this wave

    float qx[QPW], qy[QPW], qz[QPW];
    int   count[QPW], first[QPW];
    bool  havef[QPW];
    __amdgpu_buffer_rsrc_t srd[QPW];
    int* const outw = out + ((size_t)b * N_PTS + i0) * K_OUT;

    #pragma unroll
    for (int q = 0; q < QPW; ++q) {
        qx[q] = xs4[(i0 + q) * 4 + 0];
        qy[q] = xs4[(i0 + q) * 4 + 1];
        qz[q] = xs4[(i0 + q) * 4 + 2];
        count[q] = 0; first[q] = 0; havef[q] = false;
        // stride=0, num_records=256 bytes (64 int slots),
        // word3=0x00020000 = raw untyped dword access
        srd[q] = __builtin_amdgcn_make_buffer_rsrc(
            (void*)(outw + q * K_OUT), (short)0, K_OUT * 4, 0x00020000);
    }

    for (int chunk = 0; chunk < NCHUNK; ++chunk) {
        const int j = chunk * 64 + lane;
        const float4 p = *(const float4*)&xs4[j * 4];

        #pragma unroll
        for (int q = 0; q < QPW; ++q) {
            const float dx = p.x - qx[q];
            const float dy = p.y - qy[q];
            const float dz = p.z - qz[q];
            // exact numpy f32 association, no FMA contraction:
            const float d2 = __fadd_rn(__fadd_rn(__fmul_rn(dx, dx),
                                                 __fmul_rn(dy, dy)),
                                       __fmul_rn(dz, dz));
            const bool pred = d2 < R2;
            const unsigned long long mask = __ballot(pred);

            // branchless first-hit bookkeeping (wave-uniform scalar selects)
            const int cz = (mask != 0ull) ? (int)__builtin_ctzll(mask) : 0;
            first[q] = havef[q] ? first[q] : (chunk * 64 + cz);
            havef[q] = havef[q] | (mask != 0ull);

            // ascending write slot: count + prefix-popcount below this lane
            const int before = __builtin_amdgcn_mbcnt_hi(
                (unsigned int)(mask >> 32),
                __builtin_amdgcn_mbcnt_lo((unsigned int)mask, 0u));
            const unsigned pos4 = (unsigned)((count[q] + before) << 2);
            // non-pred lanes -> huge voffset (dropped); pos>=64 -> >=256 (dropped)
            const unsigned voff = pred ? pos4 : 0x40000000u;
            __builtin_amdgcn_raw_buffer_store_b32(j, srd[q], voff, 0, 0);

            count[q] += (int)__popcll(mask);           // wave-uniform
        }
    }

    // pad tails with the first hit; lanes with count+lane >= 64 are OOB-dropped
    #pragma unroll
    for (int q = 0; q < QPW; ++q) {
        const unsigned voffp = (unsigned)((count[q] + lane) << 2);
        __builtin_amdgcn_raw_buffer_store_b32(first[q], srd[q], voffp, 0, 0);
    }
}

extern "C" void kernel_launch(void* const* d_in, const int* in_sizes, int n_in,
                              void* d_out, int out_size, void* d_ws, size_t ws_size,
                              hipStream_t stream) {
    const float* pcs = (const float*)d_in[0];
    int* out = (int*)d_out;
    const int grid = B_DIM * (N_PTS / QPB);   // 1024 blocks
    ball_query_kernel<<<grid, BLOCK_T, 0, stream>>>(pcs, out);
}

// Round 9
// 89.519 us; speedup vs baseline: 1.1146x; 1.0515x over previous
//
#include <hip/hip_runtime.h>
#include <hip/hip_bf16.h>
#include <stdint.h>

// SelfBallPointQuery: B=16, C=3, N=2048, RADIUS^2=0.04, MAX_SAMPLES=64.
// For each (b,i): first 64 ascending j with |x_i - x_j|^2 < 0.04, padded with
// the first hit. int64 reference output -> int32 device buffer.
//
// R9 = R8 minus VALU bookkeeping. R8 counters back-solve to ~35 VALU/q-iter
// vs 9 of real math: the 64-bit mask ops (popcll/ctzll/!=0/selects) were
// lowered on the vector pipe. Fixes:
//  - popcount via inline asm s_bcnt1_i32_b64 (scalar pipe, hidden)
//  - first-hit tracking DELETED from the loop: slot 0 of each query's output
//    IS the first hit (count>=1 guaranteed by self-match). Read it back after
//    a vmcnt drain for the tail pad.
//  - one v_cmp serves as both ballot and cndmask selector; pos via lshl_add.
// q-iter: 13 VALU + 1 MUBUF, zero branches.

#define B_DIM 16
#define N_PTS 2048
#define K_OUT 64
#define R2 0.04f
#define QPW 4                           // queries per wave
#define WAVES_PER_BLOCK 8
#define QPB (QPW * WAVES_PER_BLOCK)     // 32 queries per block
#define NCHUNK (N_PTS / 64)             // 32
#define BLOCK_T (WAVES_PER_BLOCK * 64)  // 512

__global__ __launch_bounds__(BLOCK_T, 8) void ball_query_kernel(
    const float* __restrict__ pcs,   // (B, 3, N)
    int* __restrict__ out)           // (B, N, 64) int32
{
    __shared__ float xs4[N_PTS * 4];  // float4-padded xyz_, 32 KB

    const int b     = blockIdx.x / (N_PTS / QPB);
    const int qblk  = blockIdx.x % (N_PTS / QPB);
    const int tid   = threadIdx.x;
    const int wave  = tid >> 6;
    const int lane  = tid & 63;

    // Stage cloud b: 3 coalesced global reads per point, one b128 LDS write
    const float* src = pcs + (size_t)b * 3 * N_PTS;
    for (int j = tid; j < N_PTS; j += BLOCK_T) {
        float4 p;
        p.x = src[0 * N_PTS + j];
        p.y = src[1 * N_PTS + j];
        p.z = src[2 * N_PTS + j];
        p.w = 0.0f;
        *(float4*)&xs4[j * 4] = p;
    }
    __syncthreads();

    const int i0 = qblk * QPB + wave * QPW;    // first query of this wave

    float qx[QPW], qy[QPW], qz[QPW];
    int   count[QPW];
    __amdgpu_buffer_rsrc_t srd[QPW];
    int* const outw = out + ((size_t)b * N_PTS + i0) * K_OUT;

    #pragma unroll
    for (int q = 0; q < QPW; ++q) {
        qx[q] = xs4[(i0 + q) * 4 + 0];
        qy[q] = xs4[(i0 + q) * 4 + 1];
        qz[q] = xs4[(i0 + q) * 4 + 2];
        count[q] = 0;
        // stride=0, num_records=256 bytes (64 int slots),
        // word3=0x00020000 = raw untyped dword access
        srd[q] = __builtin_amdgcn_make_buffer_rsrc(
            (void*)(outw + q * K_OUT), (short)0, K_OUT * 4, 0x00020000);
    }

    for (int chunk = 0; chunk < NCHUNK; ++chunk) {
        const int j = chunk * 64 + lane;
        const float4 p = *(const float4*)&xs4[j * 4];

        #pragma unroll
        for (int q = 0; q < QPW; ++q) {
            const float dx = p.x - qx[q];
            const float dy = p.y - qy[q];
            const float dz = p.z - qz[q];
            // exact numpy f32 association, no FMA contraction:
            const float d2 = __fadd_rn(__fadd_rn(__fmul_rn(dx, dx),
                                                 __fmul_rn(dy, dy)),
                                       __fmul_rn(dz, dz));
            const bool pred = d2 < R2;
            const unsigned long long mask = __ballot(pred);

            // ascending write slot: count + prefix-popcount below this lane
            const int before = __builtin_amdgcn_mbcnt_hi(
                (unsigned int)(mask >> 32),
                __builtin_amdgcn_mbcnt_lo((unsigned int)mask, 0u));
            const unsigned pos4 = ((unsigned)before << 2) +
                                  (unsigned)(count[q] << 2); // v_lshl_add
            // non-pred lanes -> huge voffset (dropped); pos>=64 -> >=256 (dropped)
            const unsigned voff = pred ? pos4 : 0x40000000u;
            __builtin_amdgcn_raw_buffer_store_b32(j, srd[q], voff, 0, 0);

            // wave-uniform popcount on the SCALAR pipe
            int pc;
            asm("s_bcnt1_i32_b64 %0, %1" : "=s"(pc) : "s"(mask));
            count[q] += pc;
        }
    }

    // drain stores, then read back slot 0 = first hit (count>=1 via self-match)
    __builtin_amdgcn_s_waitcnt(0);
    int first[QPW];
    #pragma unroll
    for (int q = 0; q < QPW; ++q) first[q] = outw[q * K_OUT];

    // pad tails; lanes with count+lane >= 64 are OOB-dropped by the SRD
    #pragma unroll
    for (int q = 0; q < QPW; ++q) {
        const unsigned voffp = (unsigned)((count[q] + lane) << 2);
        __builtin_amdgcn_raw_buffer_store_b32(first[q], srd[q], voffp, 0, 0);
    }
}

extern "C" void kernel_launch(void* const* d_in, const int* in_sizes, int n_in,
                              void* d_out, int out_size, void* d_ws, size_t ws_size,
                              hipStream_t stream) {
    const float* pcs = (const float*)d_in[0];
    int* out = (int*)d_out;
    const int grid = B_DIM * (N_PTS / QPB);   // 1024 blocks
    ball_query_kernel<<<grid, BLOCK_T, 0, stream>>>(pcs, out);
}